// Round 1
// baseline (1027.558 us; speedup 1.0000x reference)
//
#include <hip/hip_runtime.h>
#include <stdint.h>

#define NJOINT 17
#define H      512
#define W      512
#define HW     (H * W)
#define TOPK   30
#define CAP    16384   // expected peaks/joint ~10.5k (HW/25); 16384 is >50 sigma margin

typedef unsigned long long u64;

// ---------------------------------------------------------------------------
// Kernel 1: 5x5 NMS (separable max via LDS) + peak collection.
// A pixel is a peak iff it equals the max of its (clipped) 5x5 window.
// Peaks are pushed as packed keys: (float_bits(value) << 32) | ~index.
// Positive-float bit patterns order correctly as uints; ~index makes
// value-ties prefer the LOWER index (matching jax.lax.top_k).
// ---------------------------------------------------------------------------
__global__ __launch_bounds__(256) void nms_collect(const float* __restrict__ heat,
                                                   u64* __restrict__ keys,
                                                   int* __restrict__ counters)
{
    __shared__ float sA[12][36];   // tile + 2-halo both dims
    __shared__ float sB[12][32];   // row-max of 5
    const int j  = blockIdx.z;
    const int bx = blockIdx.x * 32;
    const int by = blockIdx.y * 8;
    const int tx = threadIdx.x;    // 0..31
    const int ty = threadIdx.y;    // 0..7
    const int t  = ty * 32 + tx;
    const float* hj = heat + (size_t)j * HW;

    for (int i = t; i < 12 * 36; i += 256) {
        int r = i / 36, c = i % 36;
        int gy = by + r - 2, gx = bx + c - 2;
        float v = -INFINITY;
        if (gy >= 0 && gy < H && gx >= 0 && gx < W) v = hj[gy * W + gx];
        sA[r][c] = v;
    }
    __syncthreads();
    for (int i = t; i < 12 * 32; i += 256) {
        int r = i / 32, c = i % 32;
        float m = sA[r][c];
        m = fmaxf(m, sA[r][c + 1]);
        m = fmaxf(m, sA[r][c + 2]);
        m = fmaxf(m, sA[r][c + 3]);
        m = fmaxf(m, sA[r][c + 4]);
        sB[r][c] = m;
    }
    __syncthreads();
    float center = sA[ty + 2][tx + 2];
    float m = sB[ty][tx];
    m = fmaxf(m, sB[ty + 1][tx]);
    m = fmaxf(m, sB[ty + 2][tx]);
    m = fmaxf(m, sB[ty + 3][tx]);
    m = fmaxf(m, sB[ty + 4][tx]);
    // center <= m always (window contains center); equality == peak
    if (center >= m) {
        int pos = atomicAdd(&counters[j], 1);
        if (pos < CAP) {
            unsigned idx = (unsigned)((by + ty) * W + (bx + tx));
            u64 key = ((u64)__float_as_uint(center) << 32) | (u64)(~idx);
            keys[(size_t)j * CAP + pos] = key;
        }
    }
}

// ---------------------------------------------------------------------------
// Kernel 2: per-joint top-30 by repeated "max key strictly below previous
// selected key" (no mutation of the candidate array needed), then compute
// heat_xy = stride * ([x,y] + offset) for the 30 winners.
// One block per joint (17 blocks).
// ---------------------------------------------------------------------------
__global__ __launch_bounds__(256) void topk_xy(const u64* __restrict__ keys,
                                               const int* __restrict__ counters,
                                               const float* __restrict__ offs,
                                               const int* __restrict__ stride_p,
                                               float* __restrict__ heat_xy)
{
    const int j    = blockIdx.x;
    const int t    = threadIdx.x;
    const int lane = t & 63;
    const int wid  = t >> 6;
    const int cnt  = min(counters[j], CAP);
    const u64* kj  = keys + (size_t)j * CAP;

    __shared__ u64 wred[4];
    __shared__ u64 s_prev;
    __shared__ u64 sel[TOPK];

    u64 prev = ~0ull;  // sentinel: every real key is below this
    for (int r = 0; r < TOPK; ++r) {
        u64 best = 0;
        for (int i = t; i < cnt; i += 256) {
            u64 k = kj[i];
            if (k < prev && k > best) best = k;
        }
        #pragma unroll
        for (int off = 32; off > 0; off >>= 1) {
            u64 o = __shfl_down(best, off);
            if (o > best) best = o;
        }
        if (lane == 0) wred[wid] = best;
        __syncthreads();
        if (t == 0) {
            u64 b = wred[0];
            if (wred[1] > b) b = wred[1];
            if (wred[2] > b) b = wred[2];
            if (wred[3] > b) b = wred[3];
            sel[r]  = b;
            s_prev  = b;
        }
        __syncthreads();
        prev = s_prev;
    }
    if (t < TOPK) {
        u64 k = sel[t];
        float hx = 0.0f, hy = 0.0f;
        if (k != 0) {  // guard against degenerate <30-peak case
            unsigned idx = ~(unsigned)(k & 0xFFFFFFFFull);
            int xi = (int)(idx % W), yi = (int)(idx / W);
            float offx = offs[((size_t)j * 2 + 0) * HW + idx];
            float offy = offs[((size_t)j * 2 + 1) * HW + idx];
            float s = (float)(*stride_p);
            // match numpy rounding: add then multiply, no FMA contraction
            hx = __fmul_rn(s, __fadd_rn((float)xi, offx));
            hy = __fmul_rn(s, __fadd_rn((float)yi, offy));
        }
        heat_xy[(j * TOPK + t) * 2 + 0] = hx;
        heat_xy[(j * TOPK + t) * 2 + 1] = hy;
    }
}

// ---------------------------------------------------------------------------
// Kernel 3: for each (pose n, joint j) pick nearest of that joint's 30
// candidates. Pose flat index == 2*tid floats -> perfect float2 coalescing.
// Distance computed bitwise-identically to numpy (mul_rn/add_rn/sqrt_rn,
// strict < so first minimum wins, candidates in descending-value order
// exactly like top_k output).
// ---------------------------------------------------------------------------
__global__ __launch_bounds__(256) void assign_nearest(const float2* __restrict__ poses,
                                                      const float2* __restrict__ hxy,
                                                      float2* __restrict__ out,
                                                      int NJ)
{
    __shared__ float2 cand[NJOINT * TOPK];
    const int t = threadIdx.x;
    for (int i = t; i < NJOINT * TOPK; i += 256) cand[i] = hxy[i];
    __syncthreads();
    int tid = blockIdx.x * 256 + t;
    if (tid >= NJ) return;
    int j = tid % NJOINT;
    float2 p = poses[tid];
    float  bd = INFINITY;
    float2 bc = cand[j * TOPK];
    #pragma unroll
    for (int k = 0; k < TOPK; ++k) {
        float2 c  = cand[j * TOPK + k];
        float  dx = __fsub_rn(p.x, c.x);
        float  dy = __fsub_rn(p.y, c.y);
        float  d  = __fsqrt_rn(__fadd_rn(__fmul_rn(dx, dx), __fmul_rn(dy, dy)));
        if (d < bd) { bd = d; bc = c; }
    }
    out[tid] = bc;
}

extern "C" void kernel_launch(void* const* d_in, const int* in_sizes, int n_in,
                              void* d_out, int out_size, void* d_ws, size_t ws_size,
                              hipStream_t stream)
{
    const float* poses    = (const float*)d_in[0];   // (N, 34)
    const float* heat     = (const float*)d_in[1];   // (17, 512, 512)
    const float* offs     = (const float*)d_in[2];   // (17, 2, 512, 512)
    const int*   stride_p = (const int*)d_in[3];     // scalar 4

    char* ws       = (char*)d_ws;
    int*  counters = (int*)ws;                                   // 17 ints (128 B reserved)
    u64*  keys     = (u64*)(ws + 128);                           // 17*CAP u64 = 2.23 MB
    float* heat_xy = (float*)(ws + 128 + (size_t)NJOINT * CAP * 8); // 17*30*2 floats

    hipMemsetAsync(counters, 0, NJOINT * sizeof(int), stream);

    dim3 b1(32, 8, 1), g1(W / 32, H / 8, NJOINT);
    nms_collect<<<g1, b1, 0, stream>>>(heat, keys, counters);

    topk_xy<<<NJOINT, 256, 0, stream>>>(keys, counters, offs, stride_p, heat_xy);

    int NJ = (in_sizes[0] / (2 * NJOINT)) * NJOINT;  // 100000 * 17
    assign_nearest<<<(NJ + 255) / 256, 256, 0, stream>>>(
        (const float2*)poses, (const float2*)heat_xy, (float2*)d_out, NJ);
}

// Round 2
// 169.967 us; speedup vs baseline: 6.0456x; 6.0456x over previous
//
#include <hip/hip_runtime.h>
#include <stdint.h>

#define NJOINT 17
#define H      512
#define W      512
#define HW     (H * W)
#define TOPK   30
#define SLOTS  36                  // hard cap: peaks are >2 apart (Chebyshev) -> <=33 per 32x8 tile
#define BLK_X  (W / 32)            // 16
#define BLK_Y  (H / 8)             // 64
#define NBLK   (BLK_X * BLK_Y)     // 1024 tiles per joint
#define SEG_J  (NBLK * SLOTS)      // 36864 slots per joint
#define NSUB   16                  // stage-A tournament blocks per joint
#define SEGA   (SEG_J / NSUB)      // 2304 slots per stage-A block

typedef unsigned long long u64;

// ---------------------------------------------------------------------------
// Kernel 1: 5x5 NMS (separable max via LDS). ZERO global atomics: each block
// compacts its peaks via an LDS counter and writes a fixed 36-slot segment
// (unused slots = 0; key 0 never wins selection). Key = (valbits<<32) | ~idx:
// orders desc by value, ties prefer lower index (matches jax.lax.top_k).
// ---------------------------------------------------------------------------
__global__ __launch_bounds__(256) void nms_collect(const float* __restrict__ heat,
                                                   u64* __restrict__ seg)
{
    __shared__ float sA[12][36];   // tile + 2-halo both dims
    __shared__ float sB[12][32];   // row-max of 5
    __shared__ u64   blk[SLOTS];
    __shared__ int   bcnt;
    const int j  = blockIdx.z;
    const int bx = blockIdx.x * 32;
    const int by = blockIdx.y * 8;
    const int tx = threadIdx.x;    // 0..31
    const int ty = threadIdx.y;    // 0..7
    const int t  = ty * 32 + tx;
    const float* hj = heat + (size_t)j * HW;

    if (t == 0) bcnt = 0;
    for (int i = t; i < 12 * 36; i += 256) {
        int r = i / 36, c = i % 36;
        int gy = by + r - 2, gx = bx + c - 2;
        float v = -INFINITY;
        if (gy >= 0 && gy < H && gx >= 0 && gx < W) v = hj[gy * W + gx];
        sA[r][c] = v;
    }
    __syncthreads();
    for (int i = t; i < 12 * 32; i += 256) {
        int r = i / 32, c = i % 32;
        float m = sA[r][c];
        m = fmaxf(m, sA[r][c + 1]);
        m = fmaxf(m, sA[r][c + 2]);
        m = fmaxf(m, sA[r][c + 3]);
        m = fmaxf(m, sA[r][c + 4]);
        sB[r][c] = m;
    }
    __syncthreads();
    float center = sA[ty + 2][tx + 2];
    float m = sB[ty][tx];
    m = fmaxf(m, sB[ty + 1][tx]);
    m = fmaxf(m, sB[ty + 2][tx]);
    m = fmaxf(m, sB[ty + 3][tx]);
    m = fmaxf(m, sB[ty + 4][tx]);
    if (center >= m) {                      // peak (window contains center)
        int pos = atomicAdd(&bcnt, 1);      // LDS atomic — block-local, fast
        if (pos < SLOTS) {
            unsigned idx = (unsigned)((by + ty) * W + (bx + tx));
            blk[pos] = ((u64)__float_as_uint(center) << 32) | (u64)(~idx);
        }
    }
    __syncthreads();
    if (t < SLOTS) {
        int n = bcnt < SLOTS ? bcnt : SLOTS;
        size_t base = (size_t)j * SEG_J + (size_t)(blockIdx.y * BLK_X + blockIdx.x) * SLOTS;
        seg[base + t] = (t < n) ? blk[t] : 0ull;
    }
}

// ---------------------------------------------------------------------------
// Kernel 2: tournament stage A. 16 blocks per joint; each compacts its 2304
// segment slots into LDS (cannot overflow) and finds its local top-30 by
// 30 rounds of "max key strictly below previous pick" over LDS.
// ---------------------------------------------------------------------------
__global__ __launch_bounds__(256) void topk_local(const u64* __restrict__ seg,
                                                  u64* __restrict__ tops)
{
    __shared__ u64 cand[SEGA];
    __shared__ int cnt;
    __shared__ u64 wred[4];
    __shared__ u64 s_prev;
    __shared__ u64 sel[TOPK];
    const int s = blockIdx.x, j = blockIdx.y;
    const int t = threadIdx.x, lane = t & 63, wid = t >> 6;

    if (t == 0) cnt = 0;
    __syncthreads();
    const u64* base = seg + (size_t)j * SEG_J + (size_t)s * SEGA;
    for (int i = t; i < SEGA; i += 256) {
        u64 k = base[i];
        if (k) { int p = atomicAdd(&cnt, 1); cand[p] = k; }
    }
    __syncthreads();
    const int n = cnt;

    u64 prev = ~0ull;
    for (int r = 0; r < TOPK; ++r) {
        u64 best = 0;
        for (int i = t; i < n; i += 256) {
            u64 k = cand[i];
            if (k < prev && k > best) best = k;
        }
        #pragma unroll
        for (int off = 32; off > 0; off >>= 1) {
            u64 o = __shfl_down(best, off);
            if (o > best) best = o;
        }
        if (lane == 0) wred[wid] = best;
        __syncthreads();
        if (t == 0) {
            u64 b = wred[0];
            if (wred[1] > b) b = wred[1];
            if (wred[2] > b) b = wred[2];
            if (wred[3] > b) b = wred[3];
            sel[r] = b; s_prev = b;
        }
        __syncthreads();
        prev = s_prev;
    }
    if (t < TOPK) tops[((size_t)j * NSUB + s) * TOPK + t] = sel[t];
}

// ---------------------------------------------------------------------------
// Kernel 3: tournament final. Per joint, exact top-30 of the 480 stage-A
// winners (register-resident, one key per thread), then heat_xy epilogue
// with numpy-matched rounding (add_rn then mul_rn, no FMA contraction).
// ---------------------------------------------------------------------------
__global__ __launch_bounds__(512) void topk_final(const u64* __restrict__ tops,
                                                  const float* __restrict__ offs,
                                                  const int* __restrict__ stride_p,
                                                  float* __restrict__ heat_xy)
{
    const int j = blockIdx.x, t = threadIdx.x, lane = t & 63, wid = t >> 6;
    __shared__ u64 wred[8];
    __shared__ u64 s_prev;
    __shared__ u64 sel[TOPK];
    u64 myk = (t < NSUB * TOPK) ? tops[(size_t)j * NSUB * TOPK + t] : 0ull;

    u64 prev = ~0ull;
    for (int r = 0; r < TOPK; ++r) {
        u64 best = (myk < prev) ? myk : 0ull;
        #pragma unroll
        for (int off = 32; off > 0; off >>= 1) {
            u64 o = __shfl_down(best, off);
            if (o > best) best = o;
        }
        if (lane == 0) wred[wid] = best;
        __syncthreads();
        if (t == 0) {
            u64 b = wred[0];
            #pragma unroll
            for (int w = 1; w < 8; ++w) if (wred[w] > b) b = wred[w];
            sel[r] = b; s_prev = b;
        }
        __syncthreads();
        prev = s_prev;
    }
    if (t < TOPK) {
        u64 k = sel[t];
        float hx = 0.0f, hy = 0.0f;
        if (k != 0) {
            unsigned idx = ~(unsigned)(k & 0xFFFFFFFFull);
            int xi = (int)(idx & (W - 1));   // W = 512
            int yi = (int)(idx >> 9);
            float offx = offs[((size_t)j * 2 + 0) * HW + idx];
            float offy = offs[((size_t)j * 2 + 1) * HW + idx];
            float s = (float)(*stride_p);
            hx = __fmul_rn(s, __fadd_rn((float)xi, offx));
            hy = __fmul_rn(s, __fadd_rn((float)yi, offy));
        }
        heat_xy[(j * TOPK + t) * 2 + 0] = hx;
        heat_xy[(j * TOPK + t) * 2 + 1] = hy;
    }
}

// ---------------------------------------------------------------------------
// Kernel 4: nearest-candidate snap. Pose flat index == 2*tid floats ->
// perfect float2 coalescing. Distance bitwise-identical to numpy
// (mul_rn/add_rn/sqrt_rn, strict < so first minimum wins).
// ---------------------------------------------------------------------------
__global__ __launch_bounds__(256) void assign_nearest(const float2* __restrict__ poses,
                                                      const float2* __restrict__ hxy,
                                                      float2* __restrict__ out,
                                                      int NJ)
{
    __shared__ float2 cand[NJOINT * TOPK];
    const int t = threadIdx.x;
    for (int i = t; i < NJOINT * TOPK; i += 256) cand[i] = hxy[i];
    __syncthreads();
    int tid = blockIdx.x * 256 + t;
    if (tid >= NJ) return;
    int j = tid % NJOINT;
    float2 p = poses[tid];
    float  bd = INFINITY;
    float2 bc = cand[j * TOPK];
    #pragma unroll
    for (int k = 0; k < TOPK; ++k) {
        float2 c  = cand[j * TOPK + k];
        float  dx = __fsub_rn(p.x, c.x);
        float  dy = __fsub_rn(p.y, c.y);
        float  d  = __fsqrt_rn(__fadd_rn(__fmul_rn(dx, dx), __fmul_rn(dy, dy)));
        if (d < bd) { bd = d; bc = c; }
    }
    out[tid] = bc;
}

extern "C" void kernel_launch(void* const* d_in, const int* in_sizes, int n_in,
                              void* d_out, int out_size, void* d_ws, size_t ws_size,
                              hipStream_t stream)
{
    const float* poses    = (const float*)d_in[0];   // (N, 34)
    const float* heat     = (const float*)d_in[1];   // (17, 512, 512)
    const float* offs     = (const float*)d_in[2];   // (17, 2, 512, 512)
    const int*   stride_p = (const int*)d_in[3];     // scalar 4

    char* ws = (char*)d_ws;
    u64*  seg     = (u64*)ws;                                   // 17*36864*8 = 5,013,504 B
    u64*  tops    = (u64*)(ws + (size_t)NJOINT * SEG_J * 8);    // 17*480*8   = 65,280 B
    float* heat_xy = (float*)(ws + (size_t)NJOINT * SEG_J * 8
                                 + (size_t)NJOINT * NSUB * TOPK * 8); // 4,080 B

    dim3 b1(32, 8, 1), g1(BLK_X, BLK_Y, NJOINT);
    nms_collect<<<g1, b1, 0, stream>>>(heat, seg);

    dim3 g2(NSUB, NJOINT, 1);
    topk_local<<<g2, 256, 0, stream>>>(seg, tops);

    topk_final<<<NJOINT, 512, 0, stream>>>(tops, offs, stride_p, heat_xy);

    int NJ = (in_sizes[0] / (2 * NJOINT)) * NJOINT;  // 100000 * 17
    assign_nearest<<<(NJ + 255) / 256, 256, 0, stream>>>(
        (const float2*)poses, (const float2*)heat_xy, (float2*)d_out, NJ);
}

// Round 3
// 162.162 us; speedup vs baseline: 6.3366x; 1.0481x over previous
//
#include <hip/hip_runtime.h>
#include <stdint.h>

#define NJOINT 17
#define H      512
#define W      512
#define HW     (H * W)
#define TOPK   30
#define SLABH  16
#define NSLAB  (H / SLABH)        // 32 slabs per joint
#define W4     (W / 4)            // 128 float4 per row
#define CCAP   1152               // >= hard bound 1026 peaks per 512x16 slab (distinct values)

typedef unsigned long long u64;

static __device__ __forceinline__ float4 f4max(float4 a, float4 b) {
    return make_float4(fmaxf(a.x,b.x), fmaxf(a.y,b.y), fmaxf(a.z,b.z), fmaxf(a.w,b.w));
}

// ---------------------------------------------------------------------------
// Fused kernel: per (joint, 512x16 slab): separable 5x5 window-max (rowmax5
// staged in LDS, then colmax5), peak test (center == window max, -inf padding
// == reference's clipped window), LDS compaction, and single-wave top-30.
// Key = (float_bits(val) << 32) | ~idx: descending value, ties -> lower index
// (exactly jax.lax.top_k order). Keys are globally unique -> tournament exact.
// ---------------------------------------------------------------------------
__global__ __launch_bounds__(256) void nms_topk_slab(const float* __restrict__ heat,
                                                     u64* __restrict__ tops)
{
    __shared__ float4 sB[(SLABH + 4) * W4];   // rowmax5: 20*128 f4 = 40 KB
    __shared__ u64    cand[CCAP];             // 9.2 KB
    __shared__ int    cnt;
    const int s  = blockIdx.x;                // slab
    const int j  = blockIdx.y;                // joint
    const int t  = threadIdx.x;
    const int r0 = s * SLABH;
    const float4* hj4 = (const float4*)(heat + (size_t)j * HW);

    if (t == 0) cnt = 0;

    // ---- phase 1: rowmax5 for rows r0-2 .. r0+17 (20 rows) ----
    #pragma unroll
    for (int i = 0; i < (SLABH + 4) * W4 / 256; ++i) {   // 10 chunks/thread
        int chunk = t + 256 * i;
        int lr = chunk >> 7;            // local row 0..19
        int c  = chunk & (W4 - 1);      // float4 col
        int gy = r0 + lr - 2;
        float4 rm;
        if (gy < 0 || gy >= H) {
            rm = make_float4(-INFINITY, -INFINITY, -INFINITY, -INFINITY);
        } else {
            const float4* row = hj4 + (size_t)gy * W4;
            float4 Cv = row[c];
            float Lz = -INFINITY, Lw = -INFINITY, Rx = -INFINITY, Ry = -INFINITY;
            if (c > 0)      { float4 Lv = row[c - 1]; Lz = Lv.z; Lw = Lv.w; }
            if (c < W4 - 1) { float4 Rv = row[c + 1]; Rx = Rv.x; Ry = Rv.y; }
            float mCxy = fmaxf(Cv.x, Cv.y);
            float mCzw = fmaxf(Cv.z, Cv.w);
            float mCyz = fmaxf(Cv.y, Cv.z);
            rm.x = fmaxf(fmaxf(Lz, Lw), fmaxf(mCxy, Cv.z));          // x-2..x+2
            rm.y = fmaxf(Lw, fmaxf(mCxy, mCzw));                     // x-1..x+3
            rm.z = fmaxf(fmaxf(mCxy, mCzw), Rx);                     // x..x+4
            rm.w = fmaxf(mCyz, fmaxf(Cv.w, fmaxf(Rx, Ry)));          // x+1..x+5
        }
        sB[lr * W4 + c] = rm;
    }
    __syncthreads();

    // ---- phase 2: colmax5 + peak test + compaction ----
    #pragma unroll
    for (int i = 0; i < SLABH * W4 / 256; ++i) {         // 8 chunks/thread
        int chunk = t + 256 * i;
        int rr = chunk >> 7;            // slab row 0..15
        int c  = chunk & (W4 - 1);
        int gy = r0 + rr;
        float4 cen = hj4[(size_t)gy * W4 + c];           // L2-hot reload
        const float4* b = &sB[rr * W4 + c];
        float4 m = b[0];
        m = f4max(m, b[1 * W4]);
        m = f4max(m, b[2 * W4]);
        m = f4max(m, b[3 * W4]);
        m = f4max(m, b[4 * W4]);
        unsigned base_idx = (unsigned)(gy * W + 4 * c);
        if (cen.x >= m.x) { int p = atomicAdd(&cnt, 1); if (p < CCAP) cand[p] = ((u64)__float_as_uint(cen.x) << 32) | (u64)(~(base_idx + 0)); }
        if (cen.y >= m.y) { int p = atomicAdd(&cnt, 1); if (p < CCAP) cand[p] = ((u64)__float_as_uint(cen.y) << 32) | (u64)(~(base_idx + 1)); }
        if (cen.z >= m.z) { int p = atomicAdd(&cnt, 1); if (p < CCAP) cand[p] = ((u64)__float_as_uint(cen.z) << 32) | (u64)(~(base_idx + 2)); }
        if (cen.w >= m.w) { int p = atomicAdd(&cnt, 1); if (p < CCAP) cand[p] = ((u64)__float_as_uint(cen.w) << 32) | (u64)(~(base_idx + 3)); }
    }
    __syncthreads();

    // ---- phase 3: single-wave top-30 (no barriers in the loop) ----
    if (t >= 64) return;
    int n = cnt; if (n > CCAP) n = CCAP;
    u64* outp = tops + ((size_t)j * NSLAB + s) * TOPK;
    u64 prev = ~0ull;
    for (int r = 0; r < TOPK; ++r) {
        u64 best = 0;
        for (int i = t; i < n; i += 64) {
            u64 k = cand[i];
            if (k < prev && k > best) best = k;
        }
        #pragma unroll
        for (int off = 32; off > 0; off >>= 1) {
            u64 o = __shfl_down(best, off);
            if (o > best) best = o;
        }
        best = __shfl(best, 0);          // broadcast winner to all lanes
        if (t == 0) outp[r] = best;
        prev = best;
    }
}

// ---------------------------------------------------------------------------
// Final: exact top-30 of the 32*30=960 slab winners per joint; one wave,
// 15 register-resident keys per lane, no barriers in the loop. Then the
// heat_xy epilogue with numpy-matched rounding (add_rn then mul_rn).
// ---------------------------------------------------------------------------
__global__ __launch_bounds__(64) void topk_final(const u64* __restrict__ tops,
                                                 const float* __restrict__ offs,
                                                 const int* __restrict__ stride_p,
                                                 float* __restrict__ heat_xy)
{
    const int j = blockIdx.x, t = threadIdx.x;
    __shared__ u64 sel[TOPK];
    u64 k0[NSLAB * TOPK / 64];                           // 15 keys/lane
    const u64* base = tops + (size_t)j * NSLAB * TOPK;
    #pragma unroll
    for (int i = 0; i < NSLAB * TOPK / 64; ++i) k0[i] = base[t + 64 * i];

    u64 prev = ~0ull;
    for (int r = 0; r < TOPK; ++r) {
        u64 best = 0;
        #pragma unroll
        for (int i = 0; i < NSLAB * TOPK / 64; ++i) {
            u64 k = k0[i];
            if (k < prev && k > best) best = k;
        }
        #pragma unroll
        for (int off = 32; off > 0; off >>= 1) {
            u64 o = __shfl_down(best, off);
            if (o > best) best = o;
        }
        best = __shfl(best, 0);
        if (t == 0) sel[r] = best;
        prev = best;
    }
    __syncthreads();
    if (t < TOPK) {
        u64 k = sel[t];
        float hx = 0.0f, hy = 0.0f;
        if (k != 0) {
            unsigned idx = ~(unsigned)(k & 0xFFFFFFFFull);
            int xi = (int)(idx & (W - 1));
            int yi = (int)(idx >> 9);
            float offx = offs[((size_t)j * 2 + 0) * HW + idx];
            float offy = offs[((size_t)j * 2 + 1) * HW + idx];
            float sf = (float)(*stride_p);
            hx = __fmul_rn(sf, __fadd_rn((float)xi, offx));
            hy = __fmul_rn(sf, __fadd_rn((float)yi, offy));
        }
        heat_xy[(j * TOPK + t) * 2 + 0] = hx;
        heat_xy[(j * TOPK + t) * 2 + 1] = hy;
    }
}

// ---------------------------------------------------------------------------
// Nearest-candidate snap. Pose flat index == 2*tid floats -> perfect float2
// coalescing. Distance bitwise-identical to numpy (mul_rn/add_rn/sqrt_rn,
// strict < so first minimum wins; candidate order == top_k order).
// ---------------------------------------------------------------------------
__global__ __launch_bounds__(256) void assign_nearest(const float2* __restrict__ poses,
                                                      const float2* __restrict__ hxy,
                                                      float2* __restrict__ out,
                                                      int NJ)
{
    __shared__ float2 cand[NJOINT * TOPK];
    const int t = threadIdx.x;
    for (int i = t; i < NJOINT * TOPK; i += 256) cand[i] = hxy[i];
    __syncthreads();
    int tid = blockIdx.x * 256 + t;
    if (tid >= NJ) return;
    int j = tid % NJOINT;
    float2 p = poses[tid];
    float  bd = INFINITY;
    float2 bc = cand[j * TOPK];
    #pragma unroll
    for (int k = 0; k < TOPK; ++k) {
        float2 c  = cand[j * TOPK + k];
        float  dx = __fsub_rn(p.x, c.x);
        float  dy = __fsub_rn(p.y, c.y);
        float  d  = __fsqrt_rn(__fadd_rn(__fmul_rn(dx, dx), __fmul_rn(dy, dy)));
        if (d < bd) { bd = d; bc = c; }
    }
    out[tid] = bc;
}

extern "C" void kernel_launch(void* const* d_in, const int* in_sizes, int n_in,
                              void* d_out, int out_size, void* d_ws, size_t ws_size,
                              hipStream_t stream)
{
    const float* poses    = (const float*)d_in[0];   // (N, 34)
    const float* heat     = (const float*)d_in[1];   // (17, 512, 512)
    const float* offs     = (const float*)d_in[2];   // (17, 2, 512, 512)
    const int*   stride_p = (const int*)d_in[3];     // scalar 4

    char* ws = (char*)d_ws;
    u64*  tops    = (u64*)ws;                                        // 17*32*30*8 = 130,560 B
    float* heat_xy = (float*)(ws + (size_t)NJOINT * NSLAB * TOPK * 8); // 4,080 B

    dim3 g1(NSLAB, NJOINT, 1);
    nms_topk_slab<<<g1, 256, 0, stream>>>(heat, tops);

    topk_final<<<NJOINT, 64, 0, stream>>>(tops, offs, stride_p, heat_xy);

    int NJ = (in_sizes[0] / (2 * NJOINT)) * NJOINT;  // 100000 * 17
    assign_nearest<<<(NJ + 255) / 256, 256, 0, stream>>>(
        (const float2*)poses, (const float2*)heat_xy, (float2*)d_out, NJ);
}

// Round 5
// 143.171 us; speedup vs baseline: 7.1771x; 1.1326x over previous
//
#include <hip/hip_runtime.h>
#include <stdint.h>

#define NJOINT 17
#define H      512
#define W      512
#define HW     (H * W)
#define TOPK   30
#define SLABH  16
#define NSLAB  (H / SLABH)        // 32 slabs per joint
#define W4     (W / 4)            // 128 float4 per row
#define PSLOT  16                 // per-slab over-threshold key slots
#define JCAP   (NSLAB * PSLOT)    // 512 keys per joint (bitonic size)
#define LCAP   64                 // LDS staging cap per slab
#define THRESH 0.9995f            // E[over-T peaks/joint]=130 (-11 sigma to 30), per-slab E=4.1 (+6 sigma to 16)
#define FBCAP  HW                 // fallback peak buffer per joint (exact worst case)

typedef unsigned long long u64;

static __device__ __forceinline__ float4 f4max(float4 a, float4 b) {
    return make_float4(fmaxf(a.x,b.x), fmaxf(a.y,b.y), fmaxf(a.z,b.z), fmaxf(a.w,b.w));
}

// ---------------------------------------------------------------------------
// K1: 5x5 NMS per (joint, 512x16 slab) — separable rowmax5 (LDS) + colmax5.
// Peaks with value >= THRESH are compacted (LDS atomic) and written to this
// slab's fixed 16-slot segment, zero-padded (key 0 never selected). Overflow
// (>16 over-T peaks in a slab) sets a flag -> K2 takes the exact fallback.
// Key = (float_bits(val)<<32) | ~idx: desc by value, ties -> lower index
// (exactly jax.lax.top_k order); keys globally unique.
// ---------------------------------------------------------------------------
__global__ __launch_bounds__(256) void nms_collect(const float* __restrict__ heat,
                                                   u64* __restrict__ buf,    // [NJOINT][JCAP]
                                                   int* __restrict__ flags)  // [NJOINT][NSLAB]
{
    __shared__ float4 sB[(SLABH + 4) * W4];   // rowmax5: 20*128 f4 = 40 KB
    __shared__ u64    listA[LCAP];
    __shared__ int    cntA;
    const int s  = blockIdx.x;                // slab
    const int j  = blockIdx.y;                // joint
    const int t  = threadIdx.x;
    const int r0 = s * SLABH;
    const float4* hj4 = (const float4*)(heat + (size_t)j * HW);

    if (t == 0) cntA = 0;

    // ---- phase 1: rowmax5 for rows r0-2 .. r0+17 (20 rows) ----
    #pragma unroll
    for (int i = 0; i < (SLABH + 4) * W4 / 256; ++i) {   // 10 chunks/thread
        int chunk = t + 256 * i;
        int lr = chunk >> 7;            // local row 0..19
        int c  = chunk & (W4 - 1);      // float4 col
        int gy = r0 + lr - 2;
        float4 rm;
        if (gy < 0 || gy >= H) {
            rm = make_float4(-INFINITY, -INFINITY, -INFINITY, -INFINITY);
        } else {
            const float4* row = hj4 + (size_t)gy * W4;
            float4 Cv = row[c];
            float Lz = -INFINITY, Lw = -INFINITY, Rx = -INFINITY, Ry = -INFINITY;
            if (c > 0)      { float4 Lv = row[c - 1]; Lz = Lv.z; Lw = Lv.w; }
            if (c < W4 - 1) { float4 Rv = row[c + 1]; Rx = Rv.x; Ry = Rv.y; }
            float mCxy = fmaxf(Cv.x, Cv.y);
            float mCzw = fmaxf(Cv.z, Cv.w);
            float mCyz = fmaxf(Cv.y, Cv.z);
            rm.x = fmaxf(fmaxf(Lz, Lw), fmaxf(mCxy, Cv.z));          // x-2..x+2
            rm.y = fmaxf(Lw, fmaxf(mCxy, mCzw));                     // x-1..x+3
            rm.z = fmaxf(fmaxf(mCxy, mCzw), Rx);                     // x..x+4
            rm.w = fmaxf(mCyz, fmaxf(Cv.w, fmaxf(Rx, Ry)));          // x+1..x+5
        }
        sB[lr * W4 + c] = rm;
    }
    __syncthreads();

    // ---- phase 2: colmax5 + peak test + threshold filter + compaction ----
    #pragma unroll
    for (int i = 0; i < SLABH * W4 / 256; ++i) {         // 8 chunks/thread
        int chunk = t + 256 * i;
        int rr = chunk >> 7;            // slab row 0..15
        int c  = chunk & (W4 - 1);
        int gy = r0 + rr;
        float4 cen = hj4[(size_t)gy * W4 + c];           // L2-hot reload
        const float4* b = &sB[rr * W4 + c];
        float4 m = b[0];
        m = f4max(m, b[1 * W4]);
        m = f4max(m, b[2 * W4]);
        m = f4max(m, b[3 * W4]);
        m = f4max(m, b[4 * W4]);
        unsigned base_idx = (unsigned)(gy * W + 4 * c);
        if (cen.x >= m.x && cen.x >= THRESH) { int p = atomicAdd(&cntA, 1); if (p < LCAP) listA[p] = ((u64)__float_as_uint(cen.x) << 32) | (u64)(~(base_idx + 0)); }
        if (cen.y >= m.y && cen.y >= THRESH) { int p = atomicAdd(&cntA, 1); if (p < LCAP) listA[p] = ((u64)__float_as_uint(cen.y) << 32) | (u64)(~(base_idx + 1)); }
        if (cen.z >= m.z && cen.z >= THRESH) { int p = atomicAdd(&cntA, 1); if (p < LCAP) listA[p] = ((u64)__float_as_uint(cen.z) << 32) | (u64)(~(base_idx + 2)); }
        if (cen.w >= m.w && cen.w >= THRESH) { int p = atomicAdd(&cntA, 1); if (p < LCAP) listA[p] = ((u64)__float_as_uint(cen.w) << 32) | (u64)(~(base_idx + 3)); }
    }
    __syncthreads();
    int c = cntA;
    if (t < PSLOT) buf[(size_t)j * JCAP + s * PSLOT + t] = (t < c) ? listA[t] : 0ull;
    if (t == 0)    flags[j * NSLAB + s] = (c > PSLOT) ? 1 : 0;
}

// ---------------------------------------------------------------------------
// K2: per joint — bitonic sort (descending) of the 512 slot keys in LDS,
// validity check (no slab overflow, >=30 real keys), exact fallback otherwise
// (recompute NMS from heat; never taken for this data), then the heat_xy
// epilogue with numpy-matched rounding (add_rn then mul_rn, no contraction).
// ---------------------------------------------------------------------------
__global__ __launch_bounds__(256) void topk_sort(const u64* __restrict__ buf,
                                                 const int* __restrict__ flags,
                                                 const float* __restrict__ heat,
                                                 const float* __restrict__ offs,
                                                 const int* __restrict__ stride_p,
                                                 u64* __restrict__ fb,       // [NJOINT][FBCAP]
                                                 float* __restrict__ heat_xy)
{
    const int j = blockIdx.x, t = threadIdx.x;
    __shared__ u64 sk[JCAP];
    __shared__ int s_ovf;
    if (t == 0) s_ovf = 0;
    __syncthreads();
    if (t < NSLAB && flags[j * NSLAB + t]) atomicOr(&s_ovf, 1);
    for (int i = t; i < JCAP; i += 256) sk[i] = buf[(size_t)j * JCAP + i];
    __syncthreads();

    // bitonic sort, descending, N = 512
    for (int kk = 2; kk <= JCAP; kk <<= 1) {
        for (int jj = kk >> 1; jj > 0; jj >>= 1) {
            for (int i = t; i < JCAP; i += 256) {
                int p = i ^ jj;
                if (p > i) {
                    u64 a = sk[i], b = sk[p];
                    bool up = ((i & kk) == 0);       // descending region
                    if (up ? (a < b) : (a > b)) { sk[i] = b; sk[p] = a; }
                }
            }
            __syncthreads();
        }
    }

    bool ok = (s_ovf == 0) && (sk[TOPK - 1] != 0);

    if (!ok) {
        // -------- exact fallback (adversarial data only; never taken here) --------
        __shared__ int fcnt;
        __shared__ u64 wred[4];
        __shared__ u64 s_prev;
        if (t == 0) fcnt = 0;
        __syncthreads();
        const float* hj = heat + (size_t)j * HW;
        u64* fj = fb + (size_t)j * FBCAP;
        for (int p0 = t; p0 < HW; p0 += 256) {
            int y = p0 >> 9, x = p0 & (W - 1);
            float cv = hj[p0];
            float m = -INFINITY;
            for (int dy = -2; dy <= 2; ++dy) {
                int yy = y + dy; if (yy < 0 || yy >= H) continue;
                for (int dx = -2; dx <= 2; ++dx) {
                    int xx = x + dx; if (xx < 0 || xx >= W) continue;
                    m = fmaxf(m, hj[yy * W + xx]);
                }
            }
            if (cv >= m) {
                int p = atomicAdd(&fcnt, 1);
                if (p < FBCAP) fj[p] = ((u64)__float_as_uint(cv) << 32) | (u64)(~(unsigned)p0);
            }
        }
        __syncthreads();
        int n = min(fcnt, FBCAP);
        u64 prev = ~0ull;
        for (int r = 0; r < TOPK; ++r) {
            u64 best = 0;
            for (int i = t; i < n; i += 256) {
                u64 k = fj[i];
                if (k < prev && k > best) best = k;
            }
            #pragma unroll
            for (int off = 32; off > 0; off >>= 1) {
                u64 o = __shfl_down(best, off);
                if (o > best) best = o;
            }
            if ((t & 63) == 0) wred[t >> 6] = best;
            __syncthreads();
            if (t == 0) {
                u64 b = wred[0];
                for (int w = 1; w < 4; ++w) if (wred[w] > b) b = wred[w];
                sk[r] = b; s_prev = b;
            }
            __syncthreads();
            prev = s_prev;
        }
    }

    if (t < TOPK) {
        u64 k = sk[t];
        float hx = 0.0f, hy = 0.0f;
        if (k != 0) {
            unsigned idx = ~(unsigned)(k & 0xFFFFFFFFull);
            int xi = (int)(idx & (W - 1));
            int yi = (int)(idx >> 9);
            float offx = offs[((size_t)j * 2 + 0) * HW + idx];
            float offy = offs[((size_t)j * 2 + 1) * HW + idx];
            float sf = (float)(*stride_p);
            hx = __fmul_rn(sf, __fadd_rn((float)xi, offx));
            hy = __fmul_rn(sf, __fadd_rn((float)yi, offy));
        }
        heat_xy[(j * TOPK + t) * 2 + 0] = hx;
        heat_xy[(j * TOPK + t) * 2 + 1] = hy;
    }
}

// ---------------------------------------------------------------------------
// K3: nearest-candidate snap. Pose flat index == 2*tid floats -> perfect
// float2 coalescing. Distance bitwise-identical to numpy (mul_rn/add_rn/
// sqrt_rn, strict < so first minimum wins; candidate order == top_k order).
// ---------------------------------------------------------------------------
__global__ __launch_bounds__(256) void assign_nearest(const float2* __restrict__ poses,
                                                      const float2* __restrict__ hxy,
                                                      float2* __restrict__ out,
                                                      int NJ)
{
    __shared__ float2 cand[NJOINT * TOPK];
    const int t = threadIdx.x;
    for (int i = t; i < NJOINT * TOPK; i += 256) cand[i] = hxy[i];
    __syncthreads();
    int tid = blockIdx.x * 256 + t;
    if (tid >= NJ) return;
    int j = tid % NJOINT;
    float2 p = poses[tid];
    float  bd = INFINITY;
    float2 bc = cand[j * TOPK];
    #pragma unroll
    for (int k = 0; k < TOPK; ++k) {
        float2 c  = cand[j * TOPK + k];
        float  dx = __fsub_rn(p.x, c.x);
        float  dy = __fsub_rn(p.y, c.y);
        float  d  = __fsqrt_rn(__fadd_rn(__fmul_rn(dx, dx), __fmul_rn(dy, dy)));
        if (d < bd) { bd = d; bc = c; }
    }
    out[tid] = bc;
}

extern "C" void kernel_launch(void* const* d_in, const int* in_sizes, int n_in,
                              void* d_out, int out_size, void* d_ws, size_t ws_size,
                              hipStream_t stream)
{
    const float* poses    = (const float*)d_in[0];   // (N, 34)
    const float* heat     = (const float*)d_in[1];   // (17, 512, 512)
    const float* offs     = (const float*)d_in[2];   // (17, 2, 512, 512)
    const int*   stride_p = (const int*)d_in[3];     // scalar 4

    char* ws = (char*)d_ws;
    u64*   buf     = (u64*)ws;                                   // 17*512*8   = 69,632 B
    int*   flags   = (int*)(ws + (size_t)NJOINT * JCAP * 8);     // 17*32*4    = 2,176 B
    float* heat_xy = (float*)(ws + (size_t)NJOINT * JCAP * 8 + NJOINT * NSLAB * 4); // 4,080 B
    u64*   fb      = (u64*)(ws + (1 << 20));                     // fallback scratch @1 MiB, 35.7 MB

    dim3 g1(NSLAB, NJOINT, 1);
    nms_collect<<<g1, 256, 0, stream>>>(heat, buf, flags);

    topk_sort<<<NJOINT, 256, 0, stream>>>(buf, flags, heat, offs, stride_p, fb, heat_xy);

    int NJ = (in_sizes[0] / (2 * NJOINT)) * NJOINT;  // 100000 * 17
    assign_nearest<<<(NJ + 255) / 256, 256, 0, stream>>>(
        (const float2*)poses, (const float2*)heat_xy, (float2*)d_out, NJ);
}

// Round 6
// 142.450 us; speedup vs baseline: 7.2134x; 1.0051x over previous
//
#include <hip/hip_runtime.h>
#include <stdint.h>

#define NJOINT 17
#define H      512
#define W      512
#define HW     (H * W)
#define TOPK   30
#define SLABH  16
#define NSLAB  (H / SLABH)        // 32 slabs per joint
#define W4     (W / 4)            // 128 float4 per row
#define PSLOT  16                 // per-slab over-threshold key slots
#define JCAP   (NSLAB * PSLOT)    // 512 keys per joint (bitonic size)
#define LCAP   64                 // LDS staging cap per slab
#define THRESH 0.9995f            // E[over-T peaks/joint]=130 (-11 sigma to 30), per-slab E=4.1 (+6 sigma to 16)
#define FBCAP  HW                 // fallback peak buffer per joint (exact worst case)

typedef unsigned long long u64;

static __device__ __forceinline__ float4 f4max(float4 a, float4 b) {
    return make_float4(fmaxf(a.x,b.x), fmaxf(a.y,b.y), fmaxf(a.z,b.z), fmaxf(a.w,b.w));
}

// ---------------------------------------------------------------------------
// K1: 5x5 NMS per (joint, 512x16 slab) — separable rowmax5 (LDS) + colmax5.
// Phase-1 iteration i loads exactly the center float4 that phase-2 iteration
// i-1 needs (lr = rr+2, same column), so centers are cached in 8 registers
// and phase 2 touches no global memory. Peaks with value >= THRESH are
// compacted (LDS atomic) into this slab's fixed 16-slot segment, zero-padded
// (key 0 never selected). Overflow -> flag -> K2 exact fallback.
// Key = (float_bits(val)<<32) | ~idx: desc by value, ties -> lower index
// (exactly jax.lax.top_k order); keys globally unique.
// ---------------------------------------------------------------------------
__global__ __launch_bounds__(256) void nms_collect(const float* __restrict__ heat,
                                                   u64* __restrict__ buf,    // [NJOINT][JCAP]
                                                   int* __restrict__ flags)  // [NJOINT][NSLAB]
{
    __shared__ float4 sB[(SLABH + 4) * W4];   // rowmax5: 20*128 f4 = 40 KB
    __shared__ u64    listA[LCAP];
    __shared__ int    cntA;
    const int s  = blockIdx.x;                // slab
    const int j  = blockIdx.y;                // joint
    const int t  = threadIdx.x;
    const int r0 = s * SLABH;
    const float4* hj4 = (const float4*)(heat + (size_t)j * HW);

    if (t == 0) cntA = 0;

    float4 cenR[8];   // cached center rows for phase 2 (lr 2..17 == rr 0..15)

    // ---- phase 1: rowmax5 for rows r0-2 .. r0+17 (20 rows) ----
    #pragma unroll
    for (int i = 0; i < (SLABH + 4) * W4 / 256; ++i) {   // 10 chunks/thread
        int chunk = t + 256 * i;
        int lr = chunk >> 7;            // local row 0..19
        int c  = chunk & (W4 - 1);      // float4 col
        int gy = r0 + lr - 2;
        float4 rm;
        if (gy < 0 || gy >= H) {
            rm = make_float4(-INFINITY, -INFINITY, -INFINITY, -INFINITY);
        } else {
            const float4* row = hj4 + (size_t)gy * W4;
            float4 Cv = row[c];
            if (i >= 1 && i <= 8) cenR[i - 1] = Cv;      // center for phase-2 iter i-1
            float Lz = -INFINITY, Lw = -INFINITY, Rx = -INFINITY, Ry = -INFINITY;
            if (c > 0)      { float4 Lv = row[c - 1]; Lz = Lv.z; Lw = Lv.w; }
            if (c < W4 - 1) { float4 Rv = row[c + 1]; Rx = Rv.x; Ry = Rv.y; }
            float mCxy = fmaxf(Cv.x, Cv.y);
            float mCzw = fmaxf(Cv.z, Cv.w);
            float mCyz = fmaxf(Cv.y, Cv.z);
            rm.x = fmaxf(fmaxf(Lz, Lw), fmaxf(mCxy, Cv.z));          // x-2..x+2
            rm.y = fmaxf(Lw, fmaxf(mCxy, mCzw));                     // x-1..x+3
            rm.z = fmaxf(fmaxf(mCxy, mCzw), Rx);                     // x..x+4
            rm.w = fmaxf(mCyz, fmaxf(Cv.w, fmaxf(Rx, Ry)));          // x+1..x+5
        }
        sB[lr * W4 + c] = rm;
    }
    __syncthreads();

    // ---- phase 2: colmax5 + peak test + threshold filter + compaction ----
    #pragma unroll
    for (int i = 0; i < SLABH * W4 / 256; ++i) {         // 8 chunks/thread
        int chunk = t + 256 * i;
        int rr = chunk >> 7;            // slab row 0..15
        int c  = chunk & (W4 - 1);
        int gy = r0 + rr;
        float4 cen = cenR[i];           // == hj4[gy*W4 + c], cached in phase 1
        const float4* b = &sB[rr * W4 + c];
        float4 m = b[0];
        m = f4max(m, b[1 * W4]);
        m = f4max(m, b[2 * W4]);
        m = f4max(m, b[3 * W4]);
        m = f4max(m, b[4 * W4]);
        unsigned base_idx = (unsigned)(gy * W + 4 * c);
        if (cen.x >= m.x && cen.x >= THRESH) { int p = atomicAdd(&cntA, 1); if (p < LCAP) listA[p] = ((u64)__float_as_uint(cen.x) << 32) | (u64)(~(base_idx + 0)); }
        if (cen.y >= m.y && cen.y >= THRESH) { int p = atomicAdd(&cntA, 1); if (p < LCAP) listA[p] = ((u64)__float_as_uint(cen.y) << 32) | (u64)(~(base_idx + 1)); }
        if (cen.z >= m.z && cen.z >= THRESH) { int p = atomicAdd(&cntA, 1); if (p < LCAP) listA[p] = ((u64)__float_as_uint(cen.z) << 32) | (u64)(~(base_idx + 2)); }
        if (cen.w >= m.w && cen.w >= THRESH) { int p = atomicAdd(&cntA, 1); if (p < LCAP) listA[p] = ((u64)__float_as_uint(cen.w) << 32) | (u64)(~(base_idx + 3)); }
    }
    __syncthreads();
    int c = cntA;
    if (t < PSLOT) buf[(size_t)j * JCAP + s * PSLOT + t] = (t < c) ? listA[t] : 0ull;
    if (t == 0)    flags[j * NSLAB + s] = (c > PSLOT) ? 1 : 0;
}

// ---------------------------------------------------------------------------
// K2: per joint — bitonic sort (descending) of the 512 slot keys in LDS,
// validity check (no slab overflow, >=30 real keys), exact fallback otherwise
// (recompute NMS from heat; never taken for this data), then the heat_xy
// epilogue with numpy-matched rounding (add_rn then mul_rn, no contraction).
// ---------------------------------------------------------------------------
__global__ __launch_bounds__(256) void topk_sort(const u64* __restrict__ buf,
                                                 const int* __restrict__ flags,
                                                 const float* __restrict__ heat,
                                                 const float* __restrict__ offs,
                                                 const int* __restrict__ stride_p,
                                                 u64* __restrict__ fb,       // [NJOINT][FBCAP]
                                                 float* __restrict__ heat_xy)
{
    const int j = blockIdx.x, t = threadIdx.x;
    __shared__ u64 sk[JCAP];
    __shared__ int s_ovf;
    if (t == 0) s_ovf = 0;
    __syncthreads();
    if (t < NSLAB && flags[j * NSLAB + t]) atomicOr(&s_ovf, 1);
    for (int i = t; i < JCAP; i += 256) sk[i] = buf[(size_t)j * JCAP + i];
    __syncthreads();

    // bitonic sort, descending, N = 512
    for (int kk = 2; kk <= JCAP; kk <<= 1) {
        for (int jj = kk >> 1; jj > 0; jj >>= 1) {
            for (int i = t; i < JCAP; i += 256) {
                int p = i ^ jj;
                if (p > i) {
                    u64 a = sk[i], b = sk[p];
                    bool up = ((i & kk) == 0);       // descending region
                    if (up ? (a < b) : (a > b)) { sk[i] = b; sk[p] = a; }
                }
            }
            __syncthreads();
        }
    }

    bool ok = (s_ovf == 0) && (sk[TOPK - 1] != 0);

    if (!ok) {
        // -------- exact fallback (adversarial data only; never taken here) --------
        __shared__ int fcnt;
        __shared__ u64 wred[4];
        __shared__ u64 s_prev;
        if (t == 0) fcnt = 0;
        __syncthreads();
        const float* hj = heat + (size_t)j * HW;
        u64* fj = fb + (size_t)j * FBCAP;
        for (int p0 = t; p0 < HW; p0 += 256) {
            int y = p0 >> 9, x = p0 & (W - 1);
            float cv = hj[p0];
            float m = -INFINITY;
            for (int dy = -2; dy <= 2; ++dy) {
                int yy = y + dy; if (yy < 0 || yy >= H) continue;
                for (int dx = -2; dx <= 2; ++dx) {
                    int xx = x + dx; if (xx < 0 || xx >= W) continue;
                    m = fmaxf(m, hj[yy * W + xx]);
                }
            }
            if (cv >= m) {
                int p = atomicAdd(&fcnt, 1);
                if (p < FBCAP) fj[p] = ((u64)__float_as_uint(cv) << 32) | (u64)(~(unsigned)p0);
            }
        }
        __syncthreads();
        int n = min(fcnt, FBCAP);
        u64 prev = ~0ull;
        for (int r = 0; r < TOPK; ++r) {
            u64 best = 0;
            for (int i = t; i < n; i += 256) {
                u64 k = fj[i];
                if (k < prev && k > best) best = k;
            }
            #pragma unroll
            for (int off = 32; off > 0; off >>= 1) {
                u64 o = __shfl_down(best, off);
                if (o > best) best = o;
            }
            if ((t & 63) == 0) wred[t >> 6] = best;
            __syncthreads();
            if (t == 0) {
                u64 b = wred[0];
                for (int w = 1; w < 4; ++w) if (wred[w] > b) b = wred[w];
                sk[r] = b; s_prev = b;
            }
            __syncthreads();
            prev = s_prev;
        }
    }

    if (t < TOPK) {
        u64 k = sk[t];
        float hx = 0.0f, hy = 0.0f;
        if (k != 0) {
            unsigned idx = ~(unsigned)(k & 0xFFFFFFFFull);
            int xi = (int)(idx & (W - 1));
            int yi = (int)(idx >> 9);
            float offx = offs[((size_t)j * 2 + 0) * HW + idx];
            float offy = offs[((size_t)j * 2 + 1) * HW + idx];
            float sf = (float)(*stride_p);
            hx = __fmul_rn(sf, __fadd_rn((float)xi, offx));
            hy = __fmul_rn(sf, __fadd_rn((float)yi, offy));
        }
        heat_xy[(j * TOPK + t) * 2 + 0] = hx;
        heat_xy[(j * TOPK + t) * 2 + 1] = hy;
    }
}

// ---------------------------------------------------------------------------
// K3: nearest-candidate snap. Pose flat index == 2*tid floats -> perfect
// float2 coalescing. Distance bitwise-identical to numpy (mul_rn/add_rn/
// sqrt_rn, strict < so first minimum wins; candidate order == top_k order).
// Argmin tracks (dist, index) — one fewer cndmask per candidate than
// tracking coords; winner fetched from LDS once at the end.
// ---------------------------------------------------------------------------
__global__ __launch_bounds__(256) void assign_nearest(const float2* __restrict__ poses,
                                                      const float2* __restrict__ hxy,
                                                      float2* __restrict__ out,
                                                      int NJ)
{
    __shared__ float2 cand[NJOINT * TOPK];
    const int t = threadIdx.x;
    for (int i = t; i < NJOINT * TOPK; i += 256) cand[i] = hxy[i];
    __syncthreads();
    int tid = blockIdx.x * 256 + t;
    if (tid >= NJ) return;
    int j = tid % NJOINT;
    float2 p = poses[tid];
    float  bd = INFINITY;
    int    bk = 0;
    #pragma unroll
    for (int k = 0; k < TOPK; ++k) {
        float2 c  = cand[j * TOPK + k];
        float  dx = __fsub_rn(p.x, c.x);
        float  dy = __fsub_rn(p.y, c.y);
        float  d  = __fsqrt_rn(__fadd_rn(__fmul_rn(dx, dx), __fmul_rn(dy, dy)));
        if (d < bd) { bd = d; bk = k; }
    }
    out[tid] = cand[j * TOPK + bk];
}

extern "C" void kernel_launch(void* const* d_in, const int* in_sizes, int n_in,
                              void* d_out, int out_size, void* d_ws, size_t ws_size,
                              hipStream_t stream)
{
    const float* poses    = (const float*)d_in[0];   // (N, 34)
    const float* heat     = (const float*)d_in[1];   // (17, 512, 512)
    const float* offs     = (const float*)d_in[2];   // (17, 2, 512, 512)
    const int*   stride_p = (const int*)d_in[3];     // scalar 4

    char* ws = (char*)d_ws;
    u64*   buf     = (u64*)ws;                                   // 17*512*8   = 69,632 B
    int*   flags   = (int*)(ws + (size_t)NJOINT * JCAP * 8);     // 17*32*4    = 2,176 B
    float* heat_xy = (float*)(ws + (size_t)NJOINT * JCAP * 8 + NJOINT * NSLAB * 4); // 4,080 B
    u64*   fb      = (u64*)(ws + (1 << 20));                     // fallback scratch @1 MiB, 35.7 MB

    dim3 g1(NSLAB, NJOINT, 1);
    nms_collect<<<g1, 256, 0, stream>>>(heat, buf, flags);

    topk_sort<<<NJOINT, 256, 0, stream>>>(buf, flags, heat, offs, stride_p, fb, heat_xy);

    int NJ = (in_sizes[0] / (2 * NJOINT)) * NJOINT;  // 100000 * 17
    assign_nearest<<<(NJ + 255) / 256, 256, 0, stream>>>(
        (const float2*)poses, (const float2*)heat_xy, (float2*)d_out, NJ);
}